// Round 1
// baseline (34.162 us; speedup 1.0000x reference)
//
#include <hip/hip_runtime.h>

#define SPB 16   // samples per block
#define NT  256  // threads per block

__global__ __launch_bounds__(NT, 2)
void crazy_attn_kernel(const float* __restrict__ state,      // (B,100)
                       const float* __restrict__ pos_intra,  // (10,1)
                       const float* __restrict__ wq_i, const float* __restrict__ bq_i,
                       const float* __restrict__ wk_i, const float* __restrict__ bk_i,
                       const float* __restrict__ wv_i, const float* __restrict__ bv_i,
                       const float* __restrict__ pos_inter,  // (10,20)
                       const float* __restrict__ wq, const float* __restrict__ bq,
                       const float* __restrict__ wk, const float* __restrict__ bk,
                       const float* __restrict__ wv, const float* __restrict__ bv,
                       float* __restrict__ out, int B)
{
    // inter input x = intra_out + pos_inter : [samp][row=frame 10][20]
    __attribute__((aligned(16))) __shared__ float s_x[SPB * 200];
    // q/k/v rows: [samp] stride 724 (skew 4), q@0 k@240 v@480, row stride 24 (21 used)
    __attribute__((aligned(16))) __shared__ float s_qkv[SPB * 724];
    __shared__ float s_w[3 * 420];   // wq, wk, wv (20x21 each)
    __shared__ float s_b[64];        // bq(21) bk(21) bv(21)
    __shared__ float s_pos[200];     // pos_inter
    __shared__ float s_ip[24];       // pos_intra(10), wq2,bq2,wk2,bk2,wv2,bv2

    const int tid = threadIdx.x;
    const int samp0 = blockIdx.x * SPB;

    // ---- cooperative parameter loads ----
    for (int i = tid; i < 420; i += NT) {
        s_w[i] = wq[i]; s_w[420 + i] = wk[i]; s_w[840 + i] = wv[i];
    }
    for (int i = tid; i < 200; i += NT) s_pos[i] = pos_inter[i];
    if (tid < 21) { s_b[tid] = bq[tid]; s_b[21 + tid] = bk[tid]; s_b[42 + tid] = bv[tid]; }
    if (tid < 10) s_ip[tid] = pos_intra[tid];
    if (tid < 2) {
        s_ip[10 + tid] = wq_i[tid]; s_ip[12 + tid] = bq_i[tid];
        s_ip[14 + tid] = wk_i[tid]; s_ip[16 + tid] = bk_i[tid];
        s_ip[18 + tid] = wv_i[tid]; s_ip[20 + tid] = bv_i[tid];
    }
    __syncthreads();

    // ---- stage A: intra attention, one thread per (sample, frame) ----
    if (tid < SPB * 10) {
        const int samp  = tid & (SPB - 1);
        const int frame = tid >> 4;
        const int gs = samp0 + samp;
        if (gs < B) {
            const float* sp = state + (size_t)gs * 100 + frame * 10;
            float xv[10];
            #pragma unroll
            for (int t = 0; t < 10; ++t) xv[t] = sp[t] + s_ip[t];
            float res[20];
            #pragma unroll
            for (int h = 0; h < 2; ++h) {
                const float wqh = s_ip[10 + h], bqh = s_ip[12 + h];
                const float wkh = s_ip[14 + h], bkh = s_ip[16 + h];
                const float wvh = s_ip[18 + h], bvh = s_ip[20 + h];
                float qh[10], kh[10], vh[10];
                #pragma unroll
                for (int t = 0; t < 10; ++t) {
                    qh[t] = xv[t] * wqh + bqh;
                    kh[t] = xv[t] * wkh + bkh;
                    vh[t] = xv[t] * wvh + bvh;
                }
                #pragma unroll
                for (int s = 0; s < 10; ++s) {
                    float sc[10], m = -1e30f;
                    #pragma unroll
                    for (int t = 0; t < 10; ++t) { sc[t] = qh[s] * kh[t]; m = fmaxf(m, sc[t]); }
                    float sum = 0.f, o = 0.f;
                    #pragma unroll
                    for (int t = 0; t < 10; ++t) {
                        const float e = __expf(sc[t] - m);
                        sum += e; o += e * vh[t];
                    }
                    res[s * 2 + h] = o / sum;
                }
            }
            #pragma unroll
            for (int c = 0; c < 20; ++c)
                s_x[samp * 200 + frame * 20 + c] = res[c] + s_pos[frame * 20 + c];
        }
    }
    __syncthreads();

    // ---- stage B: q/k/v projections, one thread per (which, sample, row-pair) ----
    if (tid < 240) {
        const int rp    = tid % 5;
        const int samp  = (tid / 5) & (SPB - 1);
        const int which = tid / 80;          // 0=q 1=k 2=v
        const float* w  = &s_w[which * 420];
        const float* xr0 = &s_x[samp * 200 + (2 * rp) * 20];
        const float* xr1 = xr0 + 20;
        float a0[21], a1[21];
        #pragma unroll
        for (int c = 0; c < 21; ++c) { a0[c] = s_b[which * 21 + c]; a1[c] = a0[c]; }
        #pragma unroll
        for (int j = 0; j < 20; ++j) {
            const float x0 = xr0[j], x1 = xr1[j];
            #pragma unroll
            for (int c = 0; c < 21; ++c) {
                const float wv_ = w[j * 21 + c];
                a0[c] += x0 * wv_;
                a1[c] += x1 * wv_;
            }
        }
        float* dst = &s_qkv[samp * 724 + which * 240 + (2 * rp) * 24];
        #pragma unroll
        for (int c = 0; c < 21; ++c) { dst[c] = a0[c]; dst[24 + c] = a1[c]; }
    }
    __syncthreads();

    // ---- stage C: inter attention, one thread per (sample, row) ----
    if (tid < SPB * 10) {
        const int samp = tid & (SPB - 1);
        const int r    = tid >> 4;
        const int gs = samp0 + samp;
        if (gs < B) {
            const float* base = &s_qkv[samp * 724];
            float q[24];
            #pragma unroll
            for (int i = 0; i < 6; ++i)
                *(float4*)&q[i * 4] = *(const float4*)&base[r * 24 + i * 4];

            float sc[10]; float m = -1e30f;
            #pragma unroll
            for (int t = 0; t < 10; ++t) {
                float kr[24];
                #pragma unroll
                for (int i = 0; i < 6; ++i)
                    *(float4*)&kr[i * 4] = *(const float4*)&base[240 + t * 24 + i * 4];
                float d = 0.f;
                #pragma unroll
                for (int c = 0; c < 21; ++c) d += q[c] * kr[c];
                d *= 0.21821789023599239f;   // 1/sqrt(21)
                sc[t] = d; m = fmaxf(m, d);
            }
            float sum = 0.f;
            #pragma unroll
            for (int t = 0; t < 10; ++t) { sc[t] = __expf(sc[t] - m); sum += sc[t]; }
            const float inv = 1.f / sum;

            float acc[21];
            #pragma unroll
            for (int c = 0; c < 21; ++c) acc[c] = 0.f;
            #pragma unroll
            for (int t = 0; t < 10; ++t) {
                float vr[24];
                #pragma unroll
                for (int i = 0; i < 6; ++i)
                    *(float4*)&vr[i * 4] = *(const float4*)&base[480 + t * 24 + i * 4];
                const float a = sc[t] * inv;
                #pragma unroll
                for (int c = 0; c < 21; ++c) acc[c] += a * vr[c];
            }
            float* op = out + ((size_t)gs * 10 + r) * 21;
            #pragma unroll
            for (int c = 0; c < 21; ++c) op[c] = acc[c];
        }
    }
}

extern "C" void kernel_launch(void* const* d_in, const int* in_sizes, int n_in,
                              void* d_out, int out_size, void* d_ws, size_t ws_size,
                              hipStream_t stream) {
    const float* state     = (const float*)d_in[0];
    const float* pos_intra = (const float*)d_in[1];
    const float* wq_i      = (const float*)d_in[2];
    const float* bq_i      = (const float*)d_in[3];
    const float* wk_i      = (const float*)d_in[4];
    const float* bk_i      = (const float*)d_in[5];
    const float* wv_i      = (const float*)d_in[6];
    const float* bv_i      = (const float*)d_in[7];
    const float* pos_inter = (const float*)d_in[8];
    const float* wq        = (const float*)d_in[9];
    const float* bq        = (const float*)d_in[10];
    const float* wk        = (const float*)d_in[11];
    const float* bk        = (const float*)d_in[12];
    const float* wv        = (const float*)d_in[13];
    const float* bv        = (const float*)d_in[14];
    float* outp = (float*)d_out;

    const int B = in_sizes[0] / 100;
    const int grid = (B + SPB - 1) / SPB;
    hipLaunchKernelGGL(crazy_attn_kernel, dim3(grid), dim3(NT), 0, stream,
                       state, pos_intra, wq_i, bq_i, wk_i, bk_i, wv_i, bv_i,
                       pos_inter, wq, bq, wk, bk, wv, bv, outp, B);
}